// Round 7
// baseline (32.707 us; speedup 1.0000x reference)
//
#include <hip/hip_runtime.h>

#define NN 8192
#define BB 1024
#define KK 8
#define CC 10
#define NT 1024
#define CHUNK (NN/NT)    // 8
#define NW (NT/64)       // 16 waves
#define T3SZ 2100        // [0,1000): c0c1c2 | [1000,2000): c3c4c5 | [2000,2100): c6c7 (+A)

__global__ void pack_kernel(const int* __restrict__ c_in, const int* __restrict__ delta_in,
                            unsigned* __restrict__ pairs, unsigned* __restrict__ dmask_g) {
    int n = blockIdx.x * blockDim.x + threadIdx.x;
    if (n >= NN) return;
    const int4* p = reinterpret_cast<const int4*>(c_in + (size_t)n * KK);
    int4 lo = p[0], hi = p[1];
    unsigned g0 = (unsigned)((lo.x * 10 + lo.y) * 10 + lo.z);   // 0..999
    unsigned g1 = (unsigned)((lo.w * 10 + hi.x) * 10 + hi.y);   // 0..999
    unsigned g2 = (unsigned)(hi.z * 10 + hi.w);                 // 0..99
    pairs[n] = g0 | (g1 << 10) | (g2 << 20);
    unsigned long long bal = __ballot(delta_in[n] & 1);
    if ((threadIdx.x & 63) == 0) {
        dmask_g[n >> 5]       = (unsigned)(bal & 0xffffffffull);
        dmask_g[(n >> 5) + 1] = (unsigned)(bal >> 32);
    }
}

__global__ __launch_bounds__(NT, 8) void beran_kernel(
    const float* __restrict__ c_p, const float* __restrict__ bandwidth,
    const int* __restrict__ c_in, const int* __restrict__ delta_in,
    const unsigned* __restrict__ pairs, const unsigned* __restrict__ dmask_g,
    float* __restrict__ out)
{
    __shared__ float tb[KK * CC];
    __shared__ float Apart[KK];
    __shared__ float t3[T3SZ];       // negated tables, A folded into third range
    __shared__ float wsA[NW];        // additive scan slots
    __shared__ float wsM[NW];        // multiplicative scan slots

    const int b    = blockIdx.x;
    const int t    = threadIdx.x;
    const int lane = t & 63;
    const int wv   = t >> 6;
    const int base = t * CHUNK;

    // ---- softmax + per-concept metric table ----
    if (t < KK) {
        const int k = t;
        float v[CC];
        float mx = -1e30f;
        #pragma unroll
        for (int c = 0; c < CC; c++) { v[c] = c_p[((size_t)b*KK + k)*CC + c]; mx = fmaxf(mx, v[c]); }
        float se = 0.0f;
        #pragma unroll
        for (int c = 0; c < CC; c++) { v[c] = __expf(v[c] - mx); se += v[c]; }
        float inv = 1.0f / se;
        float Ak = 0.0f;
        #pragma unroll
        for (int c = 0; c < CC; c++) {
            float p  = v[c] * inv;
            float bw = bandwidth[k*CC + c];
            bw = fminf(fmaxf(bw, 0.001f), 10.0f);
            float ib = 1.0f / bw;
            tb[k*CC + c] = ib - 2.0f * p * ib;
            Ak += p * p * ib;
        }
        Apart[k] = Ak;
    }
    __syncthreads();

    // ---- build negated 3-gather tables: 2100 entries / 1024 threads ----
    for (int i = t; i < T3SZ; i += NT) {
        float v;
        if (i < 1000) {
            v = tb[0*CC + i/100] + tb[1*CC + (i/10)%10] + tb[2*CC + i%10];
        } else if (i < 2000) {
            int j = i - 1000;
            v = tb[3*CC + j/100] + tb[4*CC + (j/10)%10] + tb[5*CC + j%10];
        } else {
            int q = i - 2000;
            float Ar = 0.0f;
            #pragma unroll
            for (int k = 0; k < KK; k++) Ar += Apart[k];
            v = tb[6*CC + q/10] + tb[7*CC + q%10] + Ar;
        }
        t3[i] = -v;
    }
    __syncthreads();

    // ---- pass A (registers): raw weight cumsum, 3 LDS gathers/element ----
    float creg[CHUNK];
    unsigned dm = 0;
    float run = 0.0f;
    if (pairs) {
        dm = (dmask_g[t >> 2] >> ((t & 3) * 8)) & 0xffu;
        uint4 v0 = *reinterpret_cast<const uint4*>(pairs + base);
        uint4 v1 = *reinterpret_cast<const uint4*>(pairs + base + 4);
        unsigned pk[CHUNK] = {v0.x, v0.y, v0.z, v0.w, v1.x, v1.y, v1.z, v1.w};
        #pragma unroll
        for (int i = 0; i < CHUNK; i++) {
            unsigned w0 = pk[i];
            float m = t3[w0 & 1023] + t3[1000 + ((w0 >> 10) & 1023)]
                    + t3[2000 + (w0 >> 20)];
            run += __expf(m);          // tables hold -(A + sum t)
            creg[i] = run;
        }
    } else {
        float A = 0.0f;
        #pragma unroll
        for (int k = 0; k < KK; k++) A += Apart[k];
        #pragma unroll
        for (int i = 0; i < CHUNK; i++) {
            const int4* p4 = reinterpret_cast<const int4*>(c_in + (size_t)(base + i) * KK);
            int4 lo = p4[0], hi = p4[1];
            float m = A;
            m += tb[0*CC + lo.x] + tb[1*CC + lo.y] + tb[2*CC + lo.z] + tb[3*CC + lo.w];
            m += tb[4*CC + hi.x] + tb[5*CC + hi.y] + tb[6*CC + hi.z] + tb[7*CC + hi.w];
            run += __expf(-m);
            creg[i] = run;
            dm |= (unsigned)(delta_in[base + i] & 1) << i;
        }
    }

    // ---- scan 1 (additive): exclusive offset + total weight sum ----
    float x = run;
    #pragma unroll
    for (int d = 1; d < 64; d <<= 1) {
        float y = __shfl_up(x, d);
        if (lane >= d) x += y;
    }
    if (lane == 63) wsA[wv] = x;
    __syncthreads();
    float excl = __shfl_up(x, 1);
    if (lane == 0) excl = 0.0f;
    float s = 0.0f, woff = 0.0f;
    #pragma unroll
    for (int w = 0; w < NW; w++) {
        float y = wsA[w];             // broadcast reads
        s += y;
        if (w < wv) woff += y;
    }
    const float off_raw = woff + excl;
    const float invs = (s < 1e-13f) ? 0.0f : 1.0f / s;

    // ---- pass C (registers): telescoped hazard as a running PRODUCT ----
    // exp(-sum delta*xi) = prod over flagged i of u_i/u_{i-1}, u = 1-cs,
    // with the isclose(...,1) clamp mapping to factor = 1.
    const float ISO = 1.00001e-5f;    // atol + rtol*|1|
    float uprev = 1.0f - off_raw * invs;
    float P = 1.0f;
    #pragma unroll
    for (int i = 0; i < CHUNK; i++) {
        float cs = (creg[i] + off_raw) * invs;
        float u  = 1.0f - cs;
        bool bad  = (fabsf(uprev) <= ISO) || (fabsf(u) <= ISO);
        bool flag = (dm >> i) & 1u;
        float f = (flag && !bad) ? u * __builtin_amdgcn_rcpf(uprev) : 1.0f;
        P *= f;
        creg[i] = P;                  // inclusive local product
        uprev = u;
    }

    // ---- scan 2 (multiplicative): S_base = prod of all preceding threads ----
    float xm = P;
    #pragma unroll
    for (int d = 1; d < 64; d <<= 1) {
        float y = __shfl_up(xm, d);
        if (lane >= d) xm *= y;
    }
    if (lane == 63) wsM[wv] = xm;
    __syncthreads();
    float exclm = __shfl_up(xm, 1);
    if (lane == 0) exclm = 1.0f;
    float tot = 1.0f, moff = 1.0f;
    #pragma unroll
    for (int w = 0; w < NW; w++) {
        float y = wsM[w];             // broadcast reads
        tot *= y;
        if (w < wv) moff *= y;
    }
    const float S_base = moff * exclm;         // surv[base-1] (1 for t==0)
    const float surv_last = tot;
    const float ss = 1.0f - surv_last;         // telescoped step sum
    const float invss = (ss < 1e-13f) ? 0.0f : 1.0f / ss;

    // ---- surv into registers ----
    #pragma unroll
    for (int i = 0; i < CHUNK; i++) creg[i] = S_base * creg[i];

    const float wave_base = __shfl(S_base, 0); // surv[512*wv - 1] (1 for wave 0 of row start)
    const float g1sp     = __shfl(creg[7], 31);// surv at wave-local element 255

    // ---- epilogue: in-wave shuffle transpose -> coalesced float4 stores ----
    float* outS = out + (size_t)b * NN;
    float* outT = out + (size_t)BB * NN + (size_t)b * NN;
    const bool hi = (lane & 1);
    #pragma unroll
    for (int g = 0; g < 2; g++) {
        const int o = 32 * g + (lane >> 1);    // owner lane of this lane's 4 elems
        float e0 = __shfl(creg[0], o), e1 = __shfl(creg[1], o);
        float e2 = __shfl(creg[2], o), e3 = __shfl(creg[3], o);
        float o0 = __shfl(creg[4], o), o1 = __shfl(creg[5], o);
        float o2 = __shfl(creg[6], o), o3 = __shfl(creg[7], o);
        float s0 = hi ? o0 : e0, s1 = hi ? o1 : e1;
        float s2 = hi ? o2 : e2, s3 = hi ? o3 : e3;
        float sp = __shfl_up(s3, 1);
        if (lane == 0) sp = (g == 0) ? wave_base : g1sp;
        const int n0 = wv * 512 + g * 256 + lane * 4;
        *reinterpret_cast<float4*>(outS + n0) = make_float4(s0, s1, s2, s3);
        *reinterpret_cast<float4*>(outT + n0) =
            make_float4((sp - s0) * invss, (s0 - s1) * invss,
                        (s1 - s2) * invss, (s2 - s3) * invss);
    }
}

extern "C" void kernel_launch(void* const* d_in, const int* in_sizes, int n_in,
                              void* d_out, int out_size, void* d_ws, size_t ws_size,
                              hipStream_t stream) {
    const float* c_p       = (const float*)d_in[0];
    const float* bandwidth = (const float*)d_in[1];
    const int*   c_in      = (const int*)d_in[2];
    const int*   delta_in  = (const int*)d_in[3];
    float* out = (float*)d_out;

    unsigned* pairs   = nullptr;
    unsigned* dmask_g = nullptr;
    const size_t need = (size_t)NN * sizeof(unsigned) + (size_t)(NN / 32) * sizeof(unsigned);
    if (ws_size >= need) {
        pairs   = (unsigned*)d_ws;
        dmask_g = (unsigned*)((char*)d_ws + (size_t)NN * sizeof(unsigned));
        pack_kernel<<<NN / 256, 256, 0, stream>>>(c_in, delta_in, pairs, dmask_g);
    }
    beran_kernel<<<BB, NT, 0, stream>>>(c_p, bandwidth, c_in, delta_in, pairs, dmask_g, out);
}

// Round 8
// 28.045 us; speedup vs baseline: 1.1662x; 1.1662x over previous
//
#include <hip/hip_runtime.h>

#define NN 8192
#define BB 1024
#define KK 8
#define CC 10
#define NT 512
#define CHUNK (NN/NT)    // 16
#define NW (NT/64)       // 8 waves
#define T3SZ 2100        // [0,1000): c0c1c2 | [1000,2000): c3c4c5 | [2000,2100): c6c7 (+A)
#define HALF 4096        // epilogue stripe size

// LDS stripe-buffer swizzle: rotate column by row index -> both chunked and
// strided access patterns stay <=2-way per bank (free, per m136).
__device__ __forceinline__ int swz(int n) {
    return (n & ~31) | ((n + (n >> 5)) & 31);
}

__global__ void pack_kernel(const int* __restrict__ c_in, const int* __restrict__ delta_in,
                            unsigned* __restrict__ pairs, unsigned* __restrict__ dmask_g) {
    int n = blockIdx.x * blockDim.x + threadIdx.x;
    if (n >= NN) return;
    const int4* p = reinterpret_cast<const int4*>(c_in + (size_t)n * KK);
    int4 lo = p[0], hi = p[1];
    unsigned g0 = (unsigned)((lo.x * 10 + lo.y) * 10 + lo.z);   // 0..999
    unsigned g1 = (unsigned)((lo.w * 10 + hi.x) * 10 + hi.y);   // 0..999
    unsigned g2 = (unsigned)(hi.z * 10 + hi.w);                 // 0..99
    pairs[n] = g0 | (g1 << 10) | (g2 << 20);
    unsigned long long bal = __ballot(delta_in[n] & 1);
    if ((threadIdx.x & 63) == 0) {
        dmask_g[n >> 5]       = (unsigned)(bal & 0xffffffffull);
        dmask_g[(n >> 5) + 1] = (unsigned)(bal >> 32);
    }
}

__global__ __launch_bounds__(NT, 8) void beran_kernel(
    const float* __restrict__ c_p, const float* __restrict__ bandwidth,
    const int* __restrict__ c_in, const int* __restrict__ delta_in,
    const unsigned* __restrict__ pairs, const unsigned* __restrict__ dmask_g,
    float* __restrict__ out)
{
    __shared__ float a2[HALF];       // 16 KB swizzled stripe buffer
    __shared__ float tb[KK * CC];
    __shared__ float Apart[KK];
    __shared__ float t3[T3SZ];       // negated 3-gather tables, A folded in
    __shared__ float wsA[NW];        // additive scan slots
    __shared__ float wsM[NW];        // multiplicative scan slots
    __shared__ float s4095;          // surv at end of stripe 0

    const int b    = blockIdx.x;
    const int t    = threadIdx.x;
    const int lane = t & 63;
    const int wv   = t >> 6;
    const int base = t * CHUNK;

    // ---- softmax + per-concept metric table ----
    if (t < KK) {
        const int k = t;
        float v[CC];
        float mx = -1e30f;
        #pragma unroll
        for (int c = 0; c < CC; c++) { v[c] = c_p[((size_t)b*KK + k)*CC + c]; mx = fmaxf(mx, v[c]); }
        float se = 0.0f;
        #pragma unroll
        for (int c = 0; c < CC; c++) { v[c] = __expf(v[c] - mx); se += v[c]; }
        float inv = 1.0f / se;
        float Ak = 0.0f;
        #pragma unroll
        for (int c = 0; c < CC; c++) {
            float p  = v[c] * inv;
            float bw = bandwidth[k*CC + c];
            bw = fminf(fmaxf(bw, 0.001f), 10.0f);
            float ib = 1.0f / bw;
            tb[k*CC + c] = ib - 2.0f * p * ib;
            Ak += p * p * ib;
        }
        Apart[k] = Ak;
    }
    __syncthreads();

    // ---- build negated 3-gather tables: 2100 entries / 512 threads ----
    for (int i = t; i < T3SZ; i += NT) {
        float v;
        if (i < 1000) {
            v = tb[0*CC + i/100] + tb[1*CC + (i/10)%10] + tb[2*CC + i%10];
        } else if (i < 2000) {
            int j = i - 1000;
            v = tb[3*CC + j/100] + tb[4*CC + (j/10)%10] + tb[5*CC + j%10];
        } else {
            int q = i - 2000;
            float Ar = 0.0f;
            #pragma unroll
            for (int k = 0; k < KK; k++) Ar += Apart[k];
            v = tb[6*CC + q/10] + tb[7*CC + q%10] + Ar;
        }
        t3[i] = -v;
    }
    __syncthreads();

    // ---- pass A (registers): raw weight cumsum, 3 LDS gathers/element ----
    float creg[CHUNK];
    unsigned dm = 0;
    float run = 0.0f;
    if (pairs) {
        dm = (dmask_g[t >> 1] >> ((t & 1) * 16)) & 0xffffu;
        #pragma unroll
        for (int g = 0; g < CHUNK / 4; g++) {
            uint4 v = *reinterpret_cast<const uint4*>(pairs + base + g * 4);
#define DO3(w0, idx) { \
            float m = t3[(w0) & 1023] + t3[1000 + (((w0) >> 10) & 1023)] \
                    + t3[2000 + ((w0) >> 20)]; \
            run += __expf(m); creg[idx] = run; }
            DO3(v.x, g*4 + 0)
            DO3(v.y, g*4 + 1)
            DO3(v.z, g*4 + 2)
            DO3(v.w, g*4 + 3)
#undef DO3
        }
    } else {
        float A = 0.0f;
        #pragma unroll
        for (int k = 0; k < KK; k++) A += Apart[k];
        #pragma unroll
        for (int i = 0; i < CHUNK; i++) {
            const int4* p4 = reinterpret_cast<const int4*>(c_in + (size_t)(base + i) * KK);
            int4 lo = p4[0], hi = p4[1];
            float m = A;
            m += tb[0*CC + lo.x] + tb[1*CC + lo.y] + tb[2*CC + lo.z] + tb[3*CC + lo.w];
            m += tb[4*CC + hi.x] + tb[5*CC + hi.y] + tb[6*CC + hi.z] + tb[7*CC + hi.w];
            run += __expf(-m);
            creg[i] = run;
            dm |= (unsigned)(delta_in[base + i] & 1) << i;
        }
    }

    // ---- scan 1 (additive): exclusive offset + total weight sum ----
    float x = run;
    #pragma unroll
    for (int d = 1; d < 64; d <<= 1) {
        float y = __shfl_up(x, d);
        if (lane >= d) x += y;
    }
    if (lane == 63) wsA[wv] = x;
    __syncthreads();
    float s = 0.0f, woff = 0.0f;
    #pragma unroll
    for (int w = 0; w < NW; w++) {
        float y = wsA[w];             // broadcast reads
        s += y;
        if (w < wv) woff += y;
    }
    const float off_raw = woff + (x - run);
    const float invs = (s < 1e-13f) ? 0.0f : 1.0f / s;

    // ---- pass C (registers): telescoped hazard as a running PRODUCT ----
    // exp(-sum delta*xi) = prod over flagged i of u_i/u_{i-1}, u = 1-cs;
    // isclose(...,1) clamp on either endpoint -> factor 1.
    const float ISO = 1.00001e-5f;    // atol + rtol*|1|
    float uprev = 1.0f - off_raw * invs;
    float P = 1.0f;
    #pragma unroll
    for (int i = 0; i < CHUNK; i++) {
        float cs = (creg[i] + off_raw) * invs;
        float u  = 1.0f - cs;
        bool bad  = (fabsf(uprev) <= ISO) || (fabsf(u) <= ISO);
        bool flag = (dm >> i) & 1u;
        float f = (flag && !bad) ? u * __builtin_amdgcn_rcpf(uprev) : 1.0f;
        P *= f;
        creg[i] = P;                  // inclusive local product
        uprev = u;
    }

    // ---- scan 2 (multiplicative): S_base = product over preceding threads ----
    float xm = P;
    #pragma unroll
    for (int d = 1; d < 64; d <<= 1) {
        float y = __shfl_up(xm, d);
        if (lane >= d) xm *= y;
    }
    if (lane == 63) wsM[wv] = xm;
    __syncthreads();
    float tot = 1.0f, moff = 1.0f;
    #pragma unroll
    for (int w = 0; w < NW; w++) {
        float y = wsM[w];             // broadcast reads
        tot *= y;
        if (w < wv) moff *= y;
    }
    float exclm = __shfl_up(xm, 1);
    if (lane == 0) exclm = 1.0f;
    const float S_base = moff * exclm;          // surv[base-1] (1 for t==0)

    // ---- surv into registers; stash stripe-boundary value ----
    #pragma unroll
    for (int i = 0; i < CHUNK; i++) creg[i] = S_base * creg[i];
    if (t == NT/2) s4095 = S_base;              // surv[HALF-1]

    const float ss = 1.0f - tot;                // telescoped step sum
    const float invss = (ss < 1e-13f) ? 0.0f : 1.0f / ss;
    float* outS = out + (size_t)b * NN;
    float* outT = out + (size_t)BB * NN + (size_t)b * NN;

    // ---- striped epilogue: LDS transpose 4096 at a time, coalesced stores ----
    #pragma unroll
    for (int sidx = 0; sidx < 2; sidx++) {
        __syncthreads();              // fences prior stripe reads / scan-slot reads / s4095
        if ((t >> 8) == sidx) {
            const int lb = base - sidx * HALF;
            #pragma unroll
            for (int i = 0; i < CHUNK; i++) a2[swz(lb + i)] = creg[i];
        }
        __syncthreads();
        #pragma unroll
        for (int j = 0; j < 2; j++) {
            const int nl = j * 2048 + t * 4;    // local [0,4096)
            const int n0 = sidx * HALF + nl;    // row-global
            float s0 = a2[swz(nl)];
            float s1 = a2[swz(nl + 1)];
            float s2 = a2[swz(nl + 2)];
            float s3 = a2[swz(nl + 3)];
            float sp = (nl == 0) ? ((sidx == 0) ? 1.0f : s4095) : a2[swz(nl - 1)];
            *reinterpret_cast<float4*>(outS + n0) = make_float4(s0, s1, s2, s3);
            *reinterpret_cast<float4*>(outT + n0) =
                make_float4((sp - s0) * invss, (s0 - s1) * invss,
                            (s1 - s2) * invss, (s2 - s3) * invss);
        }
    }
}

extern "C" void kernel_launch(void* const* d_in, const int* in_sizes, int n_in,
                              void* d_out, int out_size, void* d_ws, size_t ws_size,
                              hipStream_t stream) {
    const float* c_p       = (const float*)d_in[0];
    const float* bandwidth = (const float*)d_in[1];
    const int*   c_in      = (const int*)d_in[2];
    const int*   delta_in  = (const int*)d_in[3];
    float* out = (float*)d_out;

    unsigned* pairs   = nullptr;
    unsigned* dmask_g = nullptr;
    const size_t need = (size_t)NN * sizeof(unsigned) + (size_t)(NN / 32) * sizeof(unsigned);
    if (ws_size >= need) {
        pairs   = (unsigned*)d_ws;
        dmask_g = (unsigned*)((char*)d_ws + (size_t)NN * sizeof(unsigned));
        pack_kernel<<<NN / 256, 256, 0, stream>>>(c_in, delta_in, pairs, dmask_g);
    }
    beran_kernel<<<BB, NT, 0, stream>>>(c_p, bandwidth, c_in, delta_in, pairs, dmask_g, out);
}